// Round 13
// baseline (325.500 us; speedup 1.0000x reference)
//
#include <hip/hip_runtime.h>
#include <cmath>

#define NB 8
#define NS 2048
#define ND 256
#define NH 8
#define HD 32
#define NM (NB*NS)                  // 16384 rows
#define QS_LOG2 (0.17677669529663689f * 1.4426950408889634f)  // 1/sqrt(32)*log2e
#define OUT_ATTN ((size_t)NM * ND)  // attn starts after out in d_out

typedef __attribute__((ext_vector_type(8))) short bf16x8;
typedef __attribute__((ext_vector_type(4))) float f32x4;

__device__ __forceinline__ ushort f2b(float f) {
  union { float f; uint32_t u; } v; v.f = f;
  const uint32_t r = (v.u + 0x7FFFu + ((v.u >> 16) & 1u)) >> 16;  // RNE
  return (ushort)r;
}
__device__ __forceinline__ float b2f(ushort u) {
  union { uint32_t u; float f; } v; v.u = ((uint32_t)u) << 16;
  return v.f;
}

// ---------------------------------------------------------------------------
// Kernel P: prep — split w_qkv into bf16 hi/lo; cvt w_out to bf16.
// (x is no longer pre-split: qkv reads it fp32 and splits in-register.)
// w_qkv: 49152 float4 groups | w_out: 16384 groups.
// ---------------------------------------------------------------------------
__global__ __launch_bounds__(256) void prep_kernel(
    const float* __restrict__ wq, const float* __restrict__ wo,
    ushort* __restrict__ wqh, ushort* __restrict__ wql,
    ushort* __restrict__ woh) {
  const int g = blockIdx.x * 256 + threadIdx.x;
  if (g < 49152) {
    const float4 v = ((const float4*)wq)[g];
    ushort4 h, l;
    h.x = f2b(v.x); l.x = f2b(v.x - b2f(h.x));
    h.y = f2b(v.y); l.y = f2b(v.y - b2f(h.y));
    h.z = f2b(v.z); l.z = f2b(v.z - b2f(h.z));
    h.w = f2b(v.w); l.w = f2b(v.w - b2f(h.w));
    ((ushort4*)wqh)[g] = h; ((ushort4*)wql)[g] = l;
  } else if (g < 49152 + 16384) {
    const int t = g - 49152;
    const float4 v = ((const float4*)wo)[t];
    ushort4 h;
    h.x = f2b(v.x); h.y = f2b(v.y); h.z = f2b(v.z); h.w = f2b(v.w);
    ((ushort4*)woh)[t] = h;
  }
}

// ---------------------------------------------------------------------------
// Kernel A: QKV projection via split-bf16 MFMA (near-fp32 accuracy).
// Block = 64 rows x 256 cols (3 column passes over x instead of 6 -> halves
// A-traffic); A read DIRECTLY from fp32 x, hi/lo split in-register (bit-
// identical to the old prep split). blockIdx.y == which (0=q,1=k,2=v).
// Emits: Q bf16 [bh][s][32] (prescaled by log2e/sqrt(32)), K bf16 [bh][s][32],
//        V bf16 transposed [bh][d=32][s=2048].
// ---------------------------------------------------------------------------
__global__ __launch_bounds__(256) void qkv_kernel(
    const float* __restrict__ x,
    const ushort* __restrict__ wqh, const ushort* __restrict__ wql,
    const float* __restrict__ bias,
    ushort* __restrict__ Qb, ushort* __restrict__ Kb, ushort* __restrict__ Vt) {
  __shared__ ushort Bh[256][40];   // pad 40 bf16 -> bank-benign
  __shared__ ushort Bl[256][40];
  const int m0 = blockIdx.x * 64;
  const int n0 = blockIdx.y * 256;
  const int tid  = threadIdx.x;
  const int w = tid >> 6, lane = tid & 63;
  const int a = lane & 15, qd = lane >> 4;
  const f32x4 zero4 = {0.f, 0.f, 0.f, 0.f};
  f32x4 acc[16];
#pragma unroll
  for (int i = 0; i < 16; ++i) acc[i] = zero4;

  const size_t arow = (size_t)(m0 + w*16 + a) * ND;
  const ushort* __restrict__ bh_src = wqh + (size_t)(n0 + tid) * ND;
  const ushort* __restrict__ bl_src = wql + (size_t)(n0 + tid) * ND;

  for (int ks = 0; ks < 8; ++ks) {
    const int kofs = ks * 32;
    // staging loads (each thread stages one B-row of hi AND lo)
    const bf16x8 h0 = *(const bf16x8*)&bh_src[kofs + 0];
    const bf16x8 h1 = *(const bf16x8*)&bh_src[kofs + 8];
    const bf16x8 h2 = *(const bf16x8*)&bh_src[kofs + 16];
    const bf16x8 h3 = *(const bf16x8*)&bh_src[kofs + 24];
    const bf16x8 l0 = *(const bf16x8*)&bl_src[kofs + 0];
    const bf16x8 l1 = *(const bf16x8*)&bl_src[kofs + 8];
    const bf16x8 l2 = *(const bf16x8*)&bl_src[kofs + 16];
    const bf16x8 l3 = *(const bf16x8*)&bl_src[kofs + 24];
    // A fragment: fp32 x -> in-register hi/lo split (bit-identical to prep)
    const float4 xa = *(const float4*)&x[arow + kofs + qd*8];
    const float4 xb = *(const float4*)&x[arow + kofs + qd*8 + 4];
    bf16x8 ah, al;
    {
      const float xv[8] = {xa.x, xa.y, xa.z, xa.w, xb.x, xb.y, xb.z, xb.w};
#pragma unroll
      for (int i = 0; i < 8; ++i) {
        const ushort hi = f2b(xv[i]);
        ah[i] = (short)hi;
        al[i] = (short)f2b(xv[i] - b2f(hi));
      }
    }
    __syncthreads();
    *(bf16x8*)&Bh[tid][0]  = h0;
    *(bf16x8*)&Bh[tid][8]  = h1;
    *(bf16x8*)&Bh[tid][16] = h2;
    *(bf16x8*)&Bh[tid][24] = h3;
    *(bf16x8*)&Bl[tid][0]  = l0;
    *(bf16x8*)&Bl[tid][8]  = l1;
    *(bf16x8*)&Bl[tid][16] = l2;
    *(bf16x8*)&Bl[tid][24] = l3;
    __syncthreads();
#pragma unroll
    for (int nt = 0; nt < 16; ++nt) {
      const bf16x8 bhf = *(const bf16x8*)&Bh[nt*16 + a][qd*8];
      const bf16x8 blf = *(const bf16x8*)&Bl[nt*16 + a][qd*8];
      acc[nt] = __builtin_amdgcn_mfma_f32_16x16x32_bf16(al, bhf, acc[nt], 0, 0, 0);
      acc[nt] = __builtin_amdgcn_mfma_f32_16x16x32_bf16(ah, blf, acc[nt], 0, 0, 0);
      acc[nt] = __builtin_amdgcn_mfma_f32_16x16x32_bf16(ah, bhf, acc[nt], 0, 0, 0);
    }
  }

  // epilogue: which is block-uniform; D row = qd*4+r (m), col = a
  const int which = blockIdx.y;          // 0=q 1=k 2=v
  const int mbase = m0 + w*16 + qd*4;
  const int bb = mbase >> 11, ss = mbase & 2047;
  if (which < 2) {
    const float scl = (which == 0) ? QS_LOG2 : 1.0f;
    ushort* const base = ((which == 0) ? Qb : Kb) + (size_t)(bb*NH) * NS * HD;
#pragma unroll
    for (int nt = 0; nt < 16; ++nt) {
      const int h = nt >> 1, e0 = (nt & 1)*16 + a;
      const float bz = bias[n0 + nt*16 + a];
      ushort* const dst = base + (size_t)h * NS * HD;
#pragma unroll
      for (int r = 0; r < 4; ++r)
        dst[(size_t)(ss + r) * HD + e0] = f2b((acc[nt][r] + bz) * scl);
    }
  } else {
#pragma unroll
    for (int nt = 0; nt < 16; ++nt) {
      const int h = nt >> 1, e0 = (nt & 1)*16 + a;
      const float bz = bias[n0 + nt*16 + a];
      ushort4 o;
      o.x = f2b(acc[nt][0] + bz);
      o.y = f2b(acc[nt][1] + bz);
      o.z = f2b(acc[nt][2] + bz);
      o.w = f2b(acc[nt][3] + bz);
      *(ushort4*)&Vt[((size_t)(bb*NH + h)*HD + e0) * NS + ss] = o;
    }
  }
}

// ---------------------------------------------------------------------------
// Kernel B: MFMA causal attention, fused denominators, single kernel.
// (round-12 structure, unchanged — best measured config)
// ---------------------------------------------------------------------------
__global__ __launch_bounds__(256) void attn_kernel(
    const ushort* __restrict__ Qb, const ushort* __restrict__ Kb,
    const ushort* __restrict__ Vt, float* __restrict__ attn,
    ushort* __restrict__ Om) {
  __shared__ float Ps[64][68];
  const int bh = blockIdx.x;                 // fast-varying -> per-XCD K/V L2 residency
  const int by = blockIdx.y;
  const int qt = (by & 1) ? (by >> 1) : (NS/64 - 1 - (by >> 1)); // 31,0,30,1,...
  const int q0 = qt * 64;
  const int lane = threadIdx.x & 63;
  const int w    = threadIdx.x >> 6;
  const int a    = lane & 15;
  const int qd   = lane >> 4;
  const ushort* __restrict__ Qh = Qb + (size_t)bh * NS * HD;
  const ushort* __restrict__ Kh = Kb + (size_t)bh * NS * HD;
  const ushort* __restrict__ Vh = Vt + (size_t)bh * HD * NS;

  const f32x4 zero4 = {0.f, 0.f, 0.f, 0.f};
  const bf16x8 qf = *(const bf16x8*)&Qh[(size_t)(q0 + w*16 + a) * HD + qd*8];
  float* const attnRow = attn + ((size_t)bh * NS + q0) * NS;

  // ---------------- phase 1: denom sweep ∥ zero-region stores ----------------
  bf16x8 kf[4], kn[4], vf[4], vn[4];
#pragma unroll
  for (int jt = 0; jt < 4; ++jt)
    kf[jt] = *(const bf16x8*)&Kh[(size_t)(jt*16 + a) * HD + qd*8];

  float l_l[4] = {0.f, 0.f, 0.f, 0.f};
  int zt = qt + 1;                            // next zero tile to store
  for (int kt = 0; kt <= qt; ++kt) {
    const bool diag = (kt == qt);
    const int lim = diag ? w : 3;
    if (kt < qt) {
      const int k0n = (kt + 1) * 64;
#pragma unroll
      for (int jt = 0; jt < 4; ++jt)
        kn[jt] = *(const bf16x8*)&Kh[(size_t)(k0n + jt*16 + a) * HD + qd*8];
    }
    // interleave one zero tile (store pipe; independent of MFMA/exp2 below)
    if (zt < NS / 64) {
      const int z0 = zt * 64;
#pragma unroll
      for (int i = 0; i < 4; ++i)
        __builtin_nontemporal_store(zero4,
            (f32x4*)&attnRow[(size_t)(w*16 + i*4 + qd) * NS + z0 + a*4]);
      ++zt;
    }
#pragma unroll
    for (int jt = 0; jt < 4; ++jt) {
      if (jt > lim) continue;
      const f32x4 s = __builtin_amdgcn_mfma_f32_16x16x32_bf16(qf, kf[jt], zero4, 0, 0, 0);
      if (diag && jt == w) {
#pragma unroll
        for (int r = 0; r < 4; ++r)
          l_l[r] += (a > qd*4 + r) ? 0.f : exp2f(s[r]);
      } else {
#pragma unroll
        for (int r = 0; r < 4; ++r)
          l_l[r] += exp2f(s[r]);
      }
    }
#pragma unroll
    for (int jt = 0; jt < 4; ++jt) kf[jt] = kn[jt];
  }

  // issue phase-2 tile-0 K and V loads now (hide under leftover zero stores)
#pragma unroll
  for (int jt = 0; jt < 4; ++jt)
    kf[jt] = *(const bf16x8*)&Kh[(size_t)(jt*16 + a) * HD + qd*8];
  vf[0] = *(const bf16x8*)&Vh[(size_t)(a)      * NS + qd*8];
  vf[1] = *(const bf16x8*)&Vh[(size_t)(16 + a) * NS + qd*8];
  vf[2] = *(const bf16x8*)&Vh[(size_t)(a)      * NS + 32 + qd*8];
  vf[3] = *(const bf16x8*)&Vh[(size_t)(16 + a) * NS + 32 + qd*8];

  for (; zt < NS / 64; ++zt) {               // leftover zero tiles
    const int z0 = zt * 64;
#pragma unroll
    for (int i = 0; i < 4; ++i)
      __builtin_nontemporal_store(zero4,
          (f32x4*)&attnRow[(size_t)(w*16 + i*4 + qd) * NS + z0 + a*4]);
  }

  // merge denominators across the 16-lane col group: mc = log2(sum)
  float mc[4];
#pragma unroll
  for (int r = 0; r < 4; ++r) {
    float c = l_l[r];
#pragma unroll
    for (int off = 1; off < 16; off <<= 1) c += __shfl_xor(c, off);
    mc[r] = log2f(c);
  }

  // ---------------- phase 2: compute region, K/V one tile ahead ----------------
  f32x4 oc0 = zero4, oc1 = zero4;

  for (int kt = 0; kt <= qt; ++kt) {
    const int k0 = kt * 64;
    const bool diag = (kt == qt);
    const int lim = diag ? w : 3;

    // prefetch NEXT tile's K and V (consumed next iteration)
    if (kt < qt) {
      const int k0n = k0 + 64;
#pragma unroll
      for (int jt = 0; jt < 4; ++jt)
        kn[jt] = *(const bf16x8*)&Kh[(size_t)(k0n + jt*16 + a) * HD + qd*8];
      vn[0] = *(const bf16x8*)&Vh[(size_t)(a)      * NS + k0n + qd*8];
      vn[1] = *(const bf16x8*)&Vh[(size_t)(16 + a) * NS + k0n + qd*8];
      vn[2] = *(const bf16x8*)&Vh[(size_t)(a)      * NS + k0n + 32 + qd*8];
      vn[3] = *(const bf16x8*)&Vh[(size_t)(16 + a) * NS + k0n + 32 + qd*8];
    }

    // QK -> exp2 -> Ps
#pragma unroll
    for (int jt = 0; jt < 4; ++jt) {
      if (jt > lim) {                        // masked sub-tile: zeros
#pragma unroll
        for (int r = 0; r < 4; ++r)
          Ps[w*16 + qd*4 + r][jt*16 + a] = 0.f;
        continue;
      }
      const f32x4 s = __builtin_amdgcn_mfma_f32_16x16x32_bf16(qf, kf[jt], zero4, 0, 0, 0);
      if (diag && jt == w) {
#pragma unroll
        for (int r = 0; r < 4; ++r)
          Ps[w*16 + qd*4 + r][jt*16 + a] =
              (a > qd*4 + r) ? 0.f : exp2f(s[r] - mc[r]);
      } else {
#pragma unroll
        for (int r = 0; r < 4; ++r)
          Ps[w*16 + qd*4 + r][jt*16 + a] = exp2f(s[r] - mc[r]);
      }
    }

    // coalesced nt fp32 attn write from LDS (wave-local produce/consume)
#pragma unroll
    for (int i = 0; i < 4; ++i) {
      const int row16 = i*4 + qd;
      const f32x4 pv = *(const f32x4*)&Ps[w*16 + row16][a*4];
      __builtin_nontemporal_store(pv,
          (f32x4*)&attnRow[(size_t)(w*16 + row16) * NS + k0 + a*4]);
    }

    // PV: A = P rows (bf16 cvt in-reg), B = prefetched V frags
#pragma unroll
    for (int half = 0; half < 2; ++half) {
      const float4 p0 = *(const float4*)&Ps[w*16 + a][half*32 + qd*8];
      const float4 p1 = *(const float4*)&Ps[w*16 + a][half*32 + qd*8 + 4];
      bf16x8 pa;
      pa[0] = (short)f2b(p0.x); pa[1] = (short)f2b(p0.y);
      pa[2] = (short)f2b(p0.z); pa[3] = (short)f2b(p0.w);
      pa[4] = (short)f2b(p1.x); pa[5] = (short)f2b(p1.y);
      pa[6] = (short)f2b(p1.z); pa[7] = (short)f2b(p1.w);
      oc0 = __builtin_amdgcn_mfma_f32_16x16x32_bf16(pa, half ? vf[2] : vf[0], oc0, 0, 0, 0);
      oc1 = __builtin_amdgcn_mfma_f32_16x16x32_bf16(pa, half ? vf[3] : vf[1], oc1, 0, 0, 0);
    }
#pragma unroll
    for (int jt = 0; jt < 4; ++jt) { kf[jt] = kn[jt]; vf[jt] = vn[jt]; }
  }

  // O epilogue -> bf16 Omid [16384][256] (cached: proj re-reads it)
  const int bb = bh >> 3, hh = bh & 7;
#pragma unroll
  for (int r = 0; r < 4; ++r) {
    const size_t om = (size_t)(bb * NS + q0 + w*16 + qd*4 + r) * ND + hh*32;
    Om[om + a]      = f2b(oc0[r]);
    Om[om + 16 + a] = f2b(oc1[r]);
  }
}

// ---------------------------------------------------------------------------
// Kernel C: output projection via bf16 MFMA, LDS-free.
// ---------------------------------------------------------------------------
__global__ __launch_bounds__(256) void proj_kernel(
    const ushort* __restrict__ Om, const ushort* __restrict__ woh,
    const float* __restrict__ bias, float* __restrict__ out) {
  const int m0 = blockIdx.x * 64;
  const int nb = blockIdx.y * 64;
  const int w = threadIdx.x >> 6, lane = threadIdx.x & 63;
  const int a = lane & 15, qd = lane >> 4;
  const f32x4 zero4 = {0.f, 0.f, 0.f, 0.f};
  f32x4 acc[4] = {zero4, zero4, zero4, zero4};
  const size_t arow = (size_t)(m0 + w*16 + a) * ND;
#pragma unroll
  for (int ks = 0; ks < 8; ++ks) {
    const int kofs = ks * 32 + qd * 8;
    const bf16x8 af = *(const bf16x8*)&Om[arow + kofs];
#pragma unroll
    for (int nt = 0; nt < 4; ++nt) {
      const bf16x8 bfg = *(const bf16x8*)&woh[(size_t)(nb + nt*16 + a) * ND + kofs];
      acc[nt] = __builtin_amdgcn_mfma_f32_16x16x32_bf16(af, bfg, acc[nt], 0, 0, 0);
    }
  }
#pragma unroll
  for (int nt = 0; nt < 4; ++nt) {
    const int n = nb + nt*16 + a;
    const float bz = bias[n];
#pragma unroll
    for (int r = 0; r < 4; ++r)
      out[(size_t)(m0 + w*16 + qd*4 + r) * ND + n] = acc[nt][r] + bz;
  }
}

// ---------------------------------------------------------------------------
extern "C" void kernel_launch(void* const* d_in, const int* in_sizes, int n_in,
                              void* d_out, int out_size, void* d_ws, size_t ws_size,
                              hipStream_t stream) {
  const float* x     = (const float*)d_in[0];
  const float* w_qkv = (const float*)d_in[1];
  const float* b_qkv = (const float*)d_in[2];
  const float* w_out = (const float*)d_in[3];
  const float* b_out = (const float*)d_in[4];
  float* out  = (float*)d_out;
  float* attn = out + OUT_ATTN;

  ushort* u = (ushort*)d_ws;
  const size_t SZH = (size_t)NB * NH * NS * HD;   // 4,194,304
  ushort* Qb  = u;  u += SZH;
  ushort* Kb  = u;  u += SZH;
  ushort* Vt  = u;  u += SZH;
  ushort* Om  = u;  u += SZH;
  ushort* wqh = u;  u += (size_t)768 * ND;
  ushort* wql = u;  u += (size_t)768 * ND;
  ushort* woh = u;  u += (size_t)ND * ND;

  prep_kernel<<<256, 256, 0, stream>>>(w_qkv, w_out, wqh, wql, woh);
  qkv_kernel<<<dim3(NM / 64, 3), 256, 0, stream>>>(x, wqh, wql, b_qkv, Qb, Kb, Vt);
  attn_kernel<<<dim3(NB * NH, NS / 64), 256, 0, stream>>>(Qb, Kb, Vt, attn, Om);
  proj_kernel<<<dim3(NM / 64, ND / 64), 256, 0, stream>>>(Om, woh, b_out, out);
}

// Round 14
// 307.590 us; speedup vs baseline: 1.0582x; 1.0582x over previous
//
#include <hip/hip_runtime.h>
#include <cmath>

#define NB 8
#define NS 2048
#define ND 256
#define NH 8
#define HD 32
#define NM (NB*NS)                  // 16384 rows
#define QS_LOG2 (0.17677669529663689f * 1.4426950408889634f)  // 1/sqrt(32)*log2e
#define OUT_ATTN ((size_t)NM * ND)  // attn starts after out in d_out

typedef __attribute__((ext_vector_type(8))) short bf16x8;
typedef __attribute__((ext_vector_type(4))) float f32x4;

__device__ __forceinline__ ushort f2b(float f) {
  union { float f; uint32_t u; } v; v.f = f;
  const uint32_t r = (v.u + 0x7FFFu + ((v.u >> 16) & 1u)) >> 16;  // RNE
  return (ushort)r;
}
__device__ __forceinline__ float b2f(ushort u) {
  union { uint32_t u; float f; } v; v.u = ((uint32_t)u) << 16;
  return v.f;
}

// ---------------------------------------------------------------------------
// Kernel P: prep — split x and w_qkv into bf16 hi/lo pairs; cvt w_out to bf16.
// (round-12 version, verified best)
// ---------------------------------------------------------------------------
__global__ __launch_bounds__(256) void prep_kernel(
    const float* __restrict__ x, const float* __restrict__ wq,
    const float* __restrict__ wo,
    ushort* __restrict__ xh, ushort* __restrict__ xl,
    ushort* __restrict__ wqh, ushort* __restrict__ wql,
    ushort* __restrict__ woh) {
  const int g = blockIdx.x * 256 + threadIdx.x;
  if (g < 1048576) {
    const float4 v = ((const float4*)x)[g];
    ushort4 h, l;
    h.x = f2b(v.x); l.x = f2b(v.x - b2f(h.x));
    h.y = f2b(v.y); l.y = f2b(v.y - b2f(h.y));
    h.z = f2b(v.z); l.z = f2b(v.z - b2f(h.z));
    h.w = f2b(v.w); l.w = f2b(v.w - b2f(h.w));
    ((ushort4*)xh)[g] = h; ((ushort4*)xl)[g] = l;
  } else if (g < 1048576 + 49152) {
    const int t = g - 1048576;
    const float4 v = ((const float4*)wq)[t];
    ushort4 h, l;
    h.x = f2b(v.x); l.x = f2b(v.x - b2f(h.x));
    h.y = f2b(v.y); l.y = f2b(v.y - b2f(h.y));
    h.z = f2b(v.z); l.z = f2b(v.z - b2f(h.z));
    h.w = f2b(v.w); l.w = f2b(v.w - b2f(h.w));
    ((ushort4*)wqh)[t] = h; ((ushort4*)wql)[t] = l;
  } else if (g < 1048576 + 49152 + 16384) {
    const int t = g - (1048576 + 49152);
    const float4 v = ((const float4*)wo)[t];
    ushort4 h;
    h.x = f2b(v.x); h.y = f2b(v.y); h.z = f2b(v.z); h.w = f2b(v.w);
    ((ushort4*)woh)[t] = h;
  }
}

// ---------------------------------------------------------------------------
// Kernel A: QKV projection via split-bf16 MFMA (round-12 version, best).
// Emits: Q bf16 [bh][s][32] (prescaled by log2e/sqrt(32)), K bf16 [bh][s][32],
//        V bf16 transposed [bh][d=32][s=2048].
// ---------------------------------------------------------------------------
__global__ __launch_bounds__(256) void qkv_kernel(
    const ushort* __restrict__ xh, const ushort* __restrict__ xl,
    const ushort* __restrict__ wqh, const ushort* __restrict__ wql,
    const float* __restrict__ bias,
    ushort* __restrict__ Qb, ushort* __restrict__ Kb, ushort* __restrict__ Vt) {
  __shared__ ushort Bh[128][40];   // pad 40 bf16 -> 2-way-free banks
  __shared__ ushort Bl[128][40];
  const int m0 = blockIdx.x * 64;
  const int n0 = blockIdx.y * 128;
  const int tid  = threadIdx.x;
  const int w = tid >> 6, lane = tid & 63;
  const int a = lane & 15, qd = lane >> 4;
  const int srow = tid & 127, sop = tid >> 7;   // staging: row, hi/lo select
  const f32x4 zero4 = {0.f, 0.f, 0.f, 0.f};
  f32x4 acc[8] = {zero4, zero4, zero4, zero4, zero4, zero4, zero4, zero4};

  const size_t arow = (size_t)(m0 + w*16 + a) * ND;
  const ushort* __restrict__ bsrc = (sop ? wql : wqh) + (size_t)(n0 + srow) * ND;

  for (int ks = 0; ks < 8; ++ks) {
    const int kofs = ks * 32;
    const bf16x8 t0 = *(const bf16x8*)&bsrc[kofs + 0];
    const bf16x8 t1 = *(const bf16x8*)&bsrc[kofs + 8];
    const bf16x8 t2 = *(const bf16x8*)&bsrc[kofs + 16];
    const bf16x8 t3 = *(const bf16x8*)&bsrc[kofs + 24];
    const bf16x8 ah = *(const bf16x8*)&xh[arow + kofs + qd*8];
    const bf16x8 al = *(const bf16x8*)&xl[arow + kofs + qd*8];
    __syncthreads();
    ushort (* __restrict__ Bs)[40] = sop ? Bl : Bh;
    *(bf16x8*)&Bs[srow][0]  = t0;
    *(bf16x8*)&Bs[srow][8]  = t1;
    *(bf16x8*)&Bs[srow][16] = t2;
    *(bf16x8*)&Bs[srow][24] = t3;
    __syncthreads();
#pragma unroll
    for (int nt = 0; nt < 8; ++nt) {
      const bf16x8 bhf = *(const bf16x8*)&Bh[nt*16 + a][qd*8];
      const bf16x8 blf = *(const bf16x8*)&Bl[nt*16 + a][qd*8];
      acc[nt] = __builtin_amdgcn_mfma_f32_16x16x32_bf16(al, bhf, acc[nt], 0, 0, 0);
      acc[nt] = __builtin_amdgcn_mfma_f32_16x16x32_bf16(ah, blf, acc[nt], 0, 0, 0);
      acc[nt] = __builtin_amdgcn_mfma_f32_16x16x32_bf16(ah, bhf, acc[nt], 0, 0, 0);
    }
  }

  // epilogue: D row = qd*4+r (m), col = a (n within 16-tile)
  const int mbase = m0 + w*16 + qd*4;
  const int bb = mbase >> 11, ss = mbase & 2047;
#pragma unroll
  for (int nt = 0; nt < 8; ++nt) {
    const int n = n0 + nt*16 + a;
    const int which = n >> 8;              // 0=q 1=k 2=v (uniform per nt-tile)
    const int h = (n >> 5) & 7, e0 = n & 31;
    const float bz = bias[n];
    if (which < 2) {
      const float scl = (which == 0) ? QS_LOG2 : 1.0f;
      ushort* const dst = ((which == 0) ? Qb : Kb) + (size_t)(bb*NH + h) * NS * HD;
#pragma unroll
      for (int r = 0; r < 4; ++r)
        dst[(size_t)(ss + r) * HD + e0] = f2b((acc[nt][r] + bz) * scl);
    } else {
      ushort4 o;
      o.x = f2b(acc[nt][0] + bz);
      o.y = f2b(acc[nt][1] + bz);
      o.z = f2b(acc[nt][2] + bz);
      o.w = f2b(acc[nt][3] + bz);
      *(ushort4*)&Vt[((size_t)(bb*NH + h)*HD + e0) * NS + ss] = o;
    }
  }
}

// ---------------------------------------------------------------------------
// Kernel B: MFMA causal attention, fused denominators, single kernel.
// Round-12 structure + DEFERRED PV pipeline: iteration kt computes P_kt into
// Ps[buf] (+NT attn store), then runs PV for tile kt-1 from Ps[buf^1] with
// vp (previous tile's V). V load gains ~2 tiles of latency slack at zero
// extra VGPR (vn dropped, vp added). s_setprio(1) around MFMA clusters.
// All attn stores NON-TEMPORAL (1.07 GB stream bypasses L2; K/V stay
// L2-resident). Arithmetic identical to round 12.
// ---------------------------------------------------------------------------
__global__ __launch_bounds__(256) void attn_kernel(
    const ushort* __restrict__ Qb, const ushort* __restrict__ Kb,
    const ushort* __restrict__ Vt, float* __restrict__ attn,
    ushort* __restrict__ Om) {
  __shared__ float Ps[2][64][68];            // double-buffered P
  const int bh = blockIdx.x;                 // fast-varying -> per-XCD K/V L2 residency
  const int by = blockIdx.y;
  const int qt = (by & 1) ? (by >> 1) : (NS/64 - 1 - (by >> 1)); // 31,0,30,1,...
  const int q0 = qt * 64;
  const int lane = threadIdx.x & 63;
  const int w    = threadIdx.x >> 6;
  const int a    = lane & 15;
  const int qd   = lane >> 4;
  const ushort* __restrict__ Qh = Qb + (size_t)bh * NS * HD;
  const ushort* __restrict__ Kh = Kb + (size_t)bh * NS * HD;
  const ushort* __restrict__ Vh = Vt + (size_t)bh * HD * NS;

  const f32x4 zero4 = {0.f, 0.f, 0.f, 0.f};
  const bf16x8 qf = *(const bf16x8*)&Qh[(size_t)(q0 + w*16 + a) * HD + qd*8];
  float* const attnRow = attn + ((size_t)bh * NS + q0) * NS;

  // ---------------- phase 1: denom sweep ∥ zero-region stores ----------------
  bf16x8 kf[4], kn[4], vf[4], vp[4];
#pragma unroll
  for (int jt = 0; jt < 4; ++jt)
    kf[jt] = *(const bf16x8*)&Kh[(size_t)(jt*16 + a) * HD + qd*8];

  float l_l[4] = {0.f, 0.f, 0.f, 0.f};
  int zt = qt + 1;                            // next zero tile to store
  for (int kt = 0; kt <= qt; ++kt) {
    const bool diag = (kt == qt);
    const int lim = diag ? w : 3;
    if (kt < qt) {
      const int k0n = (kt + 1) * 64;
#pragma unroll
      for (int jt = 0; jt < 4; ++jt)
        kn[jt] = *(const bf16x8*)&Kh[(size_t)(k0n + jt*16 + a) * HD + qd*8];
    }
    // interleave one zero tile (store pipe; independent of MFMA/exp2 below)
    if (zt < NS / 64) {
      const int z0 = zt * 64;
#pragma unroll
      for (int i = 0; i < 4; ++i)
        __builtin_nontemporal_store(zero4,
            (f32x4*)&attnRow[(size_t)(w*16 + i*4 + qd) * NS + z0 + a*4]);
      ++zt;
    }
    __builtin_amdgcn_s_setprio(1);
#pragma unroll
    for (int jt = 0; jt < 4; ++jt) {
      if (jt > lim) continue;
      const f32x4 s = __builtin_amdgcn_mfma_f32_16x16x32_bf16(qf, kf[jt], zero4, 0, 0, 0);
      if (diag && jt == w) {
#pragma unroll
        for (int r = 0; r < 4; ++r)
          l_l[r] += (a > qd*4 + r) ? 0.f : exp2f(s[r]);
      } else {
#pragma unroll
        for (int r = 0; r < 4; ++r)
          l_l[r] += exp2f(s[r]);
      }
    }
    __builtin_amdgcn_s_setprio(0);
#pragma unroll
    for (int jt = 0; jt < 4; ++jt) kf[jt] = kn[jt];
  }

  // issue phase-2 tile-0 K and V loads now (hide under leftover zero stores)
#pragma unroll
  for (int jt = 0; jt < 4; ++jt)
    kf[jt] = *(const bf16x8*)&Kh[(size_t)(jt*16 + a) * HD + qd*8];
  vf[0] = *(const bf16x8*)&Vh[(size_t)(a)      * NS + qd*8];
  vf[1] = *(const bf16x8*)&Vh[(size_t)(16 + a) * NS + qd*8];
  vf[2] = *(const bf16x8*)&Vh[(size_t)(a)      * NS + 32 + qd*8];
  vf[3] = *(const bf16x8*)&Vh[(size_t)(16 + a) * NS + 32 + qd*8];

  for (; zt < NS / 64; ++zt) {               // leftover zero tiles
    const int z0 = zt * 64;
#pragma unroll
    for (int i = 0; i < 4; ++i)
      __builtin_nontemporal_store(zero4,
          (f32x4*)&attnRow[(size_t)(w*16 + i*4 + qd) * NS + z0 + a*4]);
  }

  // merge denominators across the 16-lane col group: mc = log2(sum)
  float mc[4];
#pragma unroll
  for (int r = 0; r < 4; ++r) {
    float c = l_l[r];
#pragma unroll
    for (int off = 1; off < 16; off <<= 1) c += __shfl_xor(c, off);
    mc[r] = log2f(c);
  }

  // ------------- phase 2: compute region, PV deferred one tile -------------
  f32x4 oc0 = zero4, oc1 = zero4;
  int buf = 0;

  for (int kt = 0; kt <= qt; ++kt) {
    const int k0 = kt * 64;
    const bool diag = (kt == qt);
    const int lim = diag ? w : 3;

    // prefetch NEXT tile's K; load THIS tile's V (consumed next iteration)
    if (kt < qt) {
      const int k0n = k0 + 64;
#pragma unroll
      for (int jt = 0; jt < 4; ++jt)
        kn[jt] = *(const bf16x8*)&Kh[(size_t)(k0n + jt*16 + a) * HD + qd*8];
    }
    if (kt > 0) {   // tile 0's V already loaded before the zero-store tail
      vf[0] = *(const bf16x8*)&Vh[(size_t)(a)      * NS + k0 + qd*8];
      vf[1] = *(const bf16x8*)&Vh[(size_t)(16 + a) * NS + k0 + qd*8];
      vf[2] = *(const bf16x8*)&Vh[(size_t)(a)      * NS + k0 + 32 + qd*8];
      vf[3] = *(const bf16x8*)&Vh[(size_t)(16 + a) * NS + k0 + 32 + qd*8];
    }

    // QK -> exp2 -> Ps[buf]
    __builtin_amdgcn_s_setprio(1);
#pragma unroll
    for (int jt = 0; jt < 4; ++jt) {
      if (jt > lim) {                        // masked sub-tile: zeros
#pragma unroll
        for (int r = 0; r < 4; ++r)
          Ps[buf][w*16 + qd*4 + r][jt*16 + a] = 0.f;
        continue;
      }
      const f32x4 s = __builtin_amdgcn_mfma_f32_16x16x32_bf16(qf, kf[jt], zero4, 0, 0, 0);
      if (diag && jt == w) {
#pragma unroll
        for (int r = 0; r < 4; ++r)
          Ps[buf][w*16 + qd*4 + r][jt*16 + a] =
              (a > qd*4 + r) ? 0.f : exp2f(s[r] - mc[r]);
      } else {
#pragma unroll
        for (int r = 0; r < 4; ++r)
          Ps[buf][w*16 + qd*4 + r][jt*16 + a] = exp2f(s[r] - mc[r]);
      }
    }
    __builtin_amdgcn_s_setprio(0);

    // coalesced NT attn write from Ps[buf] (wave-local produce/consume)
#pragma unroll
    for (int i = 0; i < 4; ++i) {
      const int row16 = i*4 + qd;
      const f32x4 pv = *(const f32x4*)&Ps[buf][w*16 + row16][a*4];
      __builtin_nontemporal_store(pv,
          (f32x4*)&attnRow[(size_t)(w*16 + row16) * NS + k0 + a*4]);
    }

    // deferred PV for PREVIOUS tile (P has a full tile of slack; V too)
    if (kt > 0) {
      __builtin_amdgcn_s_setprio(1);
#pragma unroll
      for (int half = 0; half < 2; ++half) {
        const float4 p0 = *(const float4*)&Ps[buf ^ 1][w*16 + a][half*32 + qd*8];
        const float4 p1 = *(const float4*)&Ps[buf ^ 1][w*16 + a][half*32 + qd*8 + 4];
        bf16x8 pa;
        pa[0] = (short)f2b(p0.x); pa[1] = (short)f2b(p0.y);
        pa[2] = (short)f2b(p0.z); pa[3] = (short)f2b(p0.w);
        pa[4] = (short)f2b(p1.x); pa[5] = (short)f2b(p1.y);
        pa[6] = (short)f2b(p1.z); pa[7] = (short)f2b(p1.w);
        oc0 = __builtin_amdgcn_mfma_f32_16x16x32_bf16(pa, half ? vp[2] : vp[0], oc0, 0, 0, 0);
        oc1 = __builtin_amdgcn_mfma_f32_16x16x32_bf16(pa, half ? vp[3] : vp[1], oc1, 0, 0, 0);
      }
      __builtin_amdgcn_s_setprio(0);
    }

#pragma unroll
    for (int jt = 0; jt < 4; ++jt) { kf[jt] = kn[jt]; vp[jt] = vf[jt]; }
    buf ^= 1;
  }

  // tail: PV for the last tile (P in Ps[buf^1], V in vp)
  {
    __builtin_amdgcn_s_setprio(1);
#pragma unroll
    for (int half = 0; half < 2; ++half) {
      const float4 p0 = *(const float4*)&Ps[buf ^ 1][w*16 + a][half*32 + qd*8];
      const float4 p1 = *(const float4*)&Ps[buf ^ 1][w*16 + a][half*32 + qd*8 + 4];
      bf16x8 pa;
      pa[0] = (short)f2b(p0.x); pa[1] = (short)f2b(p0.y);
      pa[2] = (short)f2b(p0.z); pa[3] = (short)f2b(p0.w);
      pa[4] = (short)f2b(p1.x); pa[5] = (short)f2b(p1.y);
      pa[6] = (short)f2b(p1.z); pa[7] = (short)f2b(p1.w);
      oc0 = __builtin_amdgcn_mfma_f32_16x16x32_bf16(pa, half ? vp[2] : vp[0], oc0, 0, 0, 0);
      oc1 = __builtin_amdgcn_mfma_f32_16x16x32_bf16(pa, half ? vp[3] : vp[1], oc1, 0, 0, 0);
    }
    __builtin_amdgcn_s_setprio(0);
  }

  // O epilogue -> bf16 Omid [16384][256] (cached: proj re-reads it)
  const int bb = bh >> 3, hh = bh & 7;
#pragma unroll
  for (int r = 0; r < 4; ++r) {
    const size_t om = (size_t)(bb * NS + q0 + w*16 + qd*4 + r) * ND + hh*32;
    Om[om + a]      = f2b(oc0[r]);
    Om[om + 16 + a] = f2b(oc1[r]);
  }
}

// ---------------------------------------------------------------------------
// Kernel C: output projection via bf16 MFMA, LDS-free.
// ---------------------------------------------------------------------------
__global__ __launch_bounds__(256) void proj_kernel(
    const ushort* __restrict__ Om, const ushort* __restrict__ woh,
    const float* __restrict__ bias, float* __restrict__ out) {
  const int m0 = blockIdx.x * 64;
  const int nb = blockIdx.y * 64;
  const int w = threadIdx.x >> 6, lane = threadIdx.x & 63;
  const int a = lane & 15, qd = lane >> 4;
  const f32x4 zero4 = {0.f, 0.f, 0.f, 0.f};
  f32x4 acc[4] = {zero4, zero4, zero4, zero4};
  const size_t arow = (size_t)(m0 + w*16 + a) * ND;
#pragma unroll
  for (int ks = 0; ks < 8; ++ks) {
    const int kofs = ks * 32 + qd * 8;
    const bf16x8 af = *(const bf16x8*)&Om[arow + kofs];
#pragma unroll
    for (int nt = 0; nt < 4; ++nt) {
      const bf16x8 bfg = *(const bf16x8*)&woh[(size_t)(nb + nt*16 + a) * ND + kofs];
      acc[nt] = __builtin_amdgcn_mfma_f32_16x16x32_bf16(af, bfg, acc[nt], 0, 0, 0);
    }
  }
#pragma unroll
  for (int nt = 0; nt < 4; ++nt) {
    const int n = nb + nt*16 + a;
    const float bz = bias[n];
#pragma unroll
    for (int r = 0; r < 4; ++r)
      out[(size_t)(m0 + w*16 + qd*4 + r) * ND + n] = acc[nt][r] + bz;
  }
}

// ---------------------------------------------------------------------------
extern "C" void kernel_launch(void* const* d_in, const int* in_sizes, int n_in,
                              void* d_out, int out_size, void* d_ws, size_t ws_size,
                              hipStream_t stream) {
  const float* x     = (const float*)d_in[0];
  const float* w_qkv = (const float*)d_in[1];
  const float* b_qkv = (const float*)d_in[2];
  const float* w_out = (const float*)d_in[3];
  const float* b_out = (const float*)d_in[4];
  float* out  = (float*)d_out;
  float* attn = out + OUT_ATTN;

  ushort* u = (ushort*)d_ws;
  const size_t SZH = (size_t)NB * NH * NS * HD;   // 4,194,304
  ushort* Qb  = u;  u += SZH;
  ushort* Kb  = u;  u += SZH;
  ushort* Vt  = u;  u += SZH;
  ushort* Om  = u;  u += SZH;
  ushort* xh  = u;  u += SZH;
  ushort* xl  = u;  u += SZH;
  ushort* wqh = u;  u += (size_t)768 * ND;
  ushort* wql = u;  u += (size_t)768 * ND;
  ushort* woh = u;  u += (size_t)ND * ND;

  prep_kernel<<<4352, 256, 0, stream>>>(x, w_qkv, w_out, xh, xl, wqh, wql, woh);
  qkv_kernel<<<dim3(NM / 64, 768 / 128), 256, 0, stream>>>(xh, xl, wqh, wql, b_qkv, Qb, Kb, Vt);
  attn_kernel<<<dim3(NB * NH, NS / 64), 256, 0, stream>>>(Qb, Kb, Vt, attn, Om);
  proj_kernel<<<dim3(NM / 64, ND / 64), 256, 0, stream>>>(Om, woh, b_out, out);
}